// Round 6
// baseline (110.405 us; speedup 1.0000x reference)
//
#include <hip/hip_runtime.h>
#include <hip/hip_bf16.h>
#include <cstddef>

// Problem constants
#define DIMC   128
#define NHEADS 8
#define HDIM   16
#define DD     5
#define HH     24
#define WW_    48
#define NPOS   (DD * HH * WW_)     // 5760
#define SCALE  0.25f

typedef short  bf16x8 __attribute__((ext_vector_type(8)));
typedef float  f32x4  __attribute__((ext_vector_type(4)));

__device__ __forceinline__ unsigned short f2bf(float f) {
    unsigned u = __float_as_uint(f);
    u = (u + 0x7FFFu + ((u >> 16) & 1u)) >> 16;   // RNE
    return (unsigned short)u;
}
__device__ __forceinline__ float bf2f(unsigned short s) {
    return __uint_as_float(((unsigned)s) << 16);
}

// ---------------------------------------------------------------------------
// prep: fp32 -> bf16 3-term split expansion.
//   A-side (x):       [hi(128) | lo(128) | hi(128)]
//   B-side (weights): [hi(128) | hi(128) | lo(128)]
// Pairing: hi*hi + lo*hi + hi*lo == full product minus negligible lo*lo.
// ---------------------------------------------------------------------------
__global__ __launch_bounds__(256) void prep_kernel(
    const float* __restrict__ x,
    const float* __restrict__ wq,
    const float* __restrict__ wp,
    unsigned short* __restrict__ Axq,
    unsigned short* __restrict__ Bxq,
    unsigned short* __restrict__ Bxp)
{
    const int i = blockIdx.x * 256 + threadIdx.x;   // one float4 each
    const bool isA = (i < 184320);
    const float* src; unsigned short* dst; int rel;
    if (isA)             { src = x;  dst = Axq; rel = i; }
    else if (i < 196608) { src = wq; dst = Bxq; rel = i - 184320; }
    else                 { src = wp; dst = Bxp; rel = i - 196608; }
    const int row = rel >> 5;
    const int c4  = rel & 31;
    const float4 v = *(const float4*)(src + (size_t)row * 128 + c4 * 4);
    ushort4 hi, lo;
    hi.x = f2bf(v.x); hi.y = f2bf(v.y); hi.z = f2bf(v.z); hi.w = f2bf(v.w);
    lo.x = f2bf(v.x - bf2f(hi.x));
    lo.y = f2bf(v.y - bf2f(hi.y));
    lo.z = f2bf(v.z - bf2f(hi.z));
    lo.w = f2bf(v.w - bf2f(hi.w));
    unsigned short* p = dst + (size_t)row * 384 + c4 * 4;
    if (isA) {
        *(ushort4*)(p)       = hi;
        *(ushort4*)(p + 128) = lo;
        *(ushort4*)(p + 256) = hi;
    } else {
        *(ushort4*)(p)       = hi;
        *(ushort4*)(p + 128) = hi;
        *(ushort4*)(p + 256) = lo;
    }
}

// ---------------------------------------------------------------------------
// MFMA GEMM: C[M][N] = A'[M][384] @ B'[N][384]^T + bias.
// MI: rows per wave / 16. EPI 0: fp32 C out. EPI 1 (QKV): Q as bf16 hi/lo
// pairs (Qhl[pos][h*32 + {hi16|lo16}]), K/V bf16 (Kbf/Vbf[pos][128]).
// ---------------------------------------------------------------------------
template <int MI, int EPI>
__global__ __launch_bounds__(256, 3) void gemm_mfma_kernel(
    const unsigned short* __restrict__ Ax,
    const unsigned short* __restrict__ Bx,
    const float* __restrict__ bias,
    float* __restrict__ C, int ldc,
    unsigned short* __restrict__ Qhl,
    unsigned short* __restrict__ Kbf,
    unsigned short* __restrict__ Vbf)
{
    __shared__ __align__(16) unsigned short Bs[64][392];  // +16B row pad

    const int tid = threadIdx.x;
    const int bn  = blockIdx.x * 64;
    const int bm  = blockIdx.y * 64 * MI;

    for (int i = tid; i < 64 * 48; i += 256) {
        const int r = i / 48, s = i % 48;
        *(ulonglong2*)(&Bs[r][s * 8]) =
            *(const ulonglong2*)(Bx + (size_t)(bn + r) * 384 + s * 8);
    }
    __syncthreads();

    const int w    = tid >> 6;
    const int lane = tid & 63;
    const int ln   = lane & 15;
    const int quad = lane >> 4;

    f32x4 acc[MI][4] = {};
    const unsigned short* arow[MI];
    #pragma unroll
    for (int mi = 0; mi < MI; ++mi)
        arow[mi] = Ax + (size_t)(bm + w * 16 * MI + mi * 16 + ln) * 384 + quad * 8;

    #pragma unroll
    for (int kc = 0; kc < 12; ++kc) {
        bf16x8 a[MI];
        #pragma unroll
        for (int mi = 0; mi < MI; ++mi) a[mi] = *(const bf16x8*)(arow[mi] + kc * 32);
        #pragma unroll
        for (int nt = 0; nt < 4; ++nt) {
            const bf16x8 b = *(const bf16x8*)(&Bs[nt * 16 + ln][kc * 32 + quad * 8]);
            #pragma unroll
            for (int mi = 0; mi < MI; ++mi)
                acc[mi][nt] = __builtin_amdgcn_mfma_f32_16x16x32_bf16(a[mi], b, acc[mi][nt], 0, 0, 0);
        }
    }

    #pragma unroll
    for (int mi = 0; mi < MI; ++mi)
        #pragma unroll
        for (int nt = 0; nt < 4; ++nt) {
            const int col = bn + nt * 16 + ln;
            const float bv = bias[col];
            #pragma unroll
            for (int r = 0; r < 4; ++r) {
                const int row = bm + w * 16 * MI + mi * 16 + quad * 4 + r;
                const float val = acc[mi][nt][r] + bv;
                if (EPI == 0) {
                    C[(size_t)row * ldc + col] = val;
                } else {
                    if (col < 128) {               // q -> hi/lo pair
                        const int h = col >> 4, ci = col & 15;
                        const unsigned short hi = f2bf(val);
                        Qhl[(size_t)row * 256 + h * 32 + ci]      = hi;
                        Qhl[(size_t)row * 256 + h * 32 + 16 + ci] = f2bf(val - bf2f(hi));
                    } else if (col < 256) {        // k -> bf16
                        Kbf[(size_t)row * 128 + (col - 128)] = f2bf(val);
                    } else {                       // v -> bf16
                        Vbf[(size_t)row * 128 + (col - 256)] = f2bf(val);
                    }
                }
            }
        }
}

// ---------------------------------------------------------------------------
// Fused neighborhood attention, wave-per-depth-slab version.
// Grid (72 tiles of 4x4, 8 heads), 320 threads = 5 waves; wave w owns depth
// slab mt=w over ALL 512 union columns -> zero inter-wave coupling, ONE
// barrier total, no cross-wave reduction, direct global epilogue.
// S^T = K @ Q^T (K A-frags from global via RowL LUT; Q [hi|lo] in k-dim for
// fp32-grade q precision). Mask via 16-bit/tile LDS LUT. P bf16 truncate-
// packed (bias cancels: l sums the truncated values). O^T = V^T @ P^T.
// LDS 38.9 KB -> 4 blocks/CU; occupancy grid-limited (2.25 blk/CU, 11 w/CU).
// ---------------------------------------------------------------------------
__global__ __launch_bounds__(320, 2) void attn_kernel(
    const unsigned short* __restrict__ Qhl,   // [5760][256] bf16 per-head hi|lo
    const unsigned short* __restrict__ Kbf,   // [5760][128] bf16
    const unsigned short* __restrict__ Vbf,   // [5760][128] bf16
    unsigned short* __restrict__ Ap)          // [5760][384] bf16 hi|lo|hi
{
    __shared__ __align__(16) unsigned short Vt[16][520];       // 16640 B  V^T
    __shared__ __align__(16) unsigned short Qb[80][40];        //  6400 B  [hi16|lo16|pad]
    __shared__ __align__(16) unsigned short Pw[5][2][16][40];  // 12800 B  per-wave P
    __shared__ unsigned short Mb2[16][34];                     //  1088 B  mask bits [ln][tile]
    __shared__ int RowL[512];                                  //  2048 B  u -> global row

    const int tile = blockIdx.x;
    const int h    = blockIdx.y;
    const int ty0  = (tile / 12) * 4;
    const int tx0  = (tile % 12) * 4;
    const int tid  = threadIdx.x;

    // ---- RowL LUT: u -> wrapped global position (clamped for u>=500) ----
    for (int u = tid; u < 512; u += 320) {
        const int uc = u < 500 ? u : 499;
        const int dp = uc / 100, rr = uc % 100;
        const int uy = rr / 10,  ux = rr % 10;
        int y = ty0 - 3 + uy; if (y < 0) y += HH;  if (y >= HH) y -= HH;
        int x = tx0 - 3 + ux; if (x < 0) x += WW_; if (x >= WW_) x -= WW_;
        RowL[u] = (dp * HH + y) * WW_ + x;
    }
    // ---- mask LUT: Mb2[ln][t] bit b = (u=16t+b valid for query ln) ----
    for (int i = tid; i < 512; i += 320) {
        const int t = i >> 4, ln = i & 15;
        const int sy = ln >> 2, sx = ln & 3;
        unsigned bits = 0;
        #pragma unroll
        for (int b = 0; b < 16; ++b) {
            const int u = t * 16 + b;
            const int rr = u % 100;
            const int uy = rr / 10, ux = rr % 10;
            if (u < 500 && (unsigned)(uy - sy) <= 6u && (unsigned)(ux - sx) <= 6u)
                bits |= 1u << b;
        }
        Mb2[ln][t] = (unsigned short)bits;
    }
    // ---- stage V^T: item = u-pair, dword-packed writes ----
    for (int i = tid; i < 256; i += 320) {
        const int u0 = i * 2;
        unsigned short va[16], vb[16];
        #pragma unroll
        for (int c = 0; c < 16; ++c) { va[c] = 0; vb[c] = 0; }
        #pragma unroll
        for (int half = 0; half < 2; ++half) {
            const int u = u0 + half;
            if (u < 500) {
                const int dp = u / 100, rr = u % 100;
                const int uy = rr / 10,  ux = rr % 10;
                int y = ty0 - 3 + uy; if (y < 0) y += HH;  if (y >= HH) y -= HH;
                int x = tx0 - 3 + ux; if (x < 0) x += WW_; if (x >= WW_) x -= WW_;
                const int g = (dp * HH + y) * WW_ + x;
                const bf16x8 p0 = *(const bf16x8*)(Vbf + (size_t)g * 128 + h * 16);
                const bf16x8 p1 = *(const bf16x8*)(Vbf + (size_t)g * 128 + h * 16 + 8);
                unsigned short* dst = half ? vb : va;
                #pragma unroll
                for (int c = 0; c < 8; ++c) { dst[c] = (unsigned short)p0[c]; dst[8 + c] = (unsigned short)p1[c]; }
            }
        }
        #pragma unroll
        for (int c = 0; c < 16; ++c)
            *(unsigned*)(&Vt[c][u0]) = (unsigned)va[c] | ((unsigned)vb[c] << 16);
    }
    // ---- stage Q tile (320 items == 320 threads) ----
    {
        const int p = tid >> 2, seg = tid & 3;
        const int d = p >> 4, s = p & 15;
        const int sy = s >> 2, sx = s & 3;
        const int g = (d * HH + ty0 + sy) * WW_ + tx0 + sx;
        *(bf16x8*)(&Qb[p][seg * 8]) = *(const bf16x8*)(Qhl + (size_t)g * 256 + h * 32 + seg * 8);
    }
    __syncthreads();   // the only barrier

    const int w    = tid >> 6;    // wave = depth slab mt
    const int lane = tid & 63;
    const int ln   = lane & 15;
    const int quad = lane >> 4;

    const bf16x8 qf = *(const bf16x8*)(&Qb[w * 16 + ln][quad * 8]);
    f32x4 Ow = {0.f, 0.f, 0.f, 0.f};
    float lsum = 0.f;

    const float C1 = SCALE * 1.44269504f;   // log2(e)*scale
    const float C0 = -11.5415603f;          // -8*log2(e) (shift cancels in softmax)

    #pragma unroll 4
    for (int c = 0; c < 16; ++c) {
        const int u0 = c * 32;
        const int g0 = RowL[u0 + ln];
        const int g1 = RowL[u0 + 16 + ln];
        const bf16x8 k0 = *(const bf16x8*)(Kbf + (size_t)g0 * 128 + h * 16 + (quad & 1) * 8);
        const bf16x8 k1 = *(const bf16x8*)(Kbf + (size_t)g1 * 128 + h * 16 + (quad & 1) * 8);
        const unsigned mb = *(const unsigned*)(&Mb2[ln][2 * c]);   // tiles 2c|2c+1
        const unsigned m0 = (mb >> (quad * 4)) & 0xF;
        const unsigned m1 = (mb >> (16 + quad * 4)) & 0xF;

        f32x4 s0 = __builtin_amdgcn_mfma_f32_16x16x32_bf16(k0, qf, (f32x4){0.f,0.f,0.f,0.f}, 0, 0, 0);
        f32x4 s1 = __builtin_amdgcn_mfma_f32_16x16x32_bf16(k1, qf, (f32x4){0.f,0.f,0.f,0.f}, 0, 0, 0);

        unsigned short* pw = &Pw[w][c & 1][ln][0];
        #pragma unroll
        for (int t = 0; t < 2; ++t) {
            const f32x4 s = t ? s1 : s0;
            const unsigned m = t ? m1 : m0;
            unsigned eu[4];
            #pragma unroll
            for (int r = 0; r < 4; ++r) {
                const float arg = ((m >> r) & 1u) ? fmaf(s[r], C1, C0) : -100.f;
                const unsigned trunc = __float_as_uint(exp2f(arg)) & 0xFFFF0000u;
                eu[r] = trunc;
                lsum += __uint_as_float(trunc);
            }
            unsigned* dst = (unsigned*)(pw + t * 16 + quad * 4);
            dst[0] = (eu[0] >> 16) | eu[1];
            dst[1] = (eu[2] >> 16) | eu[3];
        }

        const bf16x8 vf = *(const bf16x8*)(&Vt[ln][u0 + quad * 8]);
        const bf16x8 pf = *(const bf16x8*)(&Pw[w][c & 1][ln][quad * 8]);
        Ow = __builtin_amdgcn_mfma_f32_16x16x32_bf16(vf, pf, Ow, 0, 0, 0);
    }

    // ---- l: reduce across quads (lanes ln+16q hold disjoint u-partials) ----
    lsum += __shfl_xor(lsum, 16);
    lsum += __shfl_xor(lsum, 32);
    const float inv = 1.0f / lsum;

    // ---- epilogue: lane holds O^T[ch=quad*4+r][query=ln], write Ap ----
    const int sy = ln >> 2, sx = ln & 3;
    const size_t g = (size_t)((w * HH + ty0 + sy) * WW_ + (tx0 + sx));
    ushort4 hi4, lo4;
    {
        float v0 = Ow[0] * inv, v1 = Ow[1] * inv, v2 = Ow[2] * inv, v3 = Ow[3] * inv;
        hi4.x = f2bf(v0); lo4.x = f2bf(v0 - bf2f(hi4.x));
        hi4.y = f2bf(v1); lo4.y = f2bf(v1 - bf2f(hi4.y));
        hi4.z = f2bf(v2); lo4.z = f2bf(v2 - bf2f(hi4.z));
        hi4.w = f2bf(v3); lo4.w = f2bf(v3 - bf2f(hi4.w));
    }
    unsigned short* row = Ap + g * 384 + h * HDIM + quad * 4;
    *(ushort4*)(row)       = hi4;
    *(ushort4*)(row + 128) = lo4;
    *(ushort4*)(row + 256) = hi4;
}

// ---------------------------------------------------------------------------
extern "C" void kernel_launch(void* const* d_in, const int* in_sizes, int n_in,
                              void* d_out, int out_size, void* d_ws, size_t ws_size,
                              hipStream_t stream)
{
    const float* x      = (const float*)d_in[0];
    const float* qkv_w  = (const float*)d_in[1];
    const float* qkv_b  = (const float*)d_in[2];
    const float* proj_w = (const float*)d_in[3];
    const float* proj_b = (const float*)d_in[4];
    float* out = (float*)d_out;

    char* ws = (char*)d_ws;
    unsigned short* Axq = (unsigned short*)ws;  ws += (size_t)NPOS * 384 * 2;  // x  hi|lo|hi
    unsigned short* Ap  = (unsigned short*)ws;  ws += (size_t)NPOS * 384 * 2;  // attn out hi|lo|hi
    unsigned short* Bxq = (unsigned short*)ws;  ws += (size_t)384 * 384 * 2;
    unsigned short* Bxp = (unsigned short*)ws;  ws += (size_t)128 * 384 * 2;
    unsigned short* Qhl = (unsigned short*)ws;  ws += (size_t)NPOS * 256 * 2;  // q hi|lo per head
    unsigned short* Kbf = (unsigned short*)ws;  ws += (size_t)NPOS * 128 * 2;
    unsigned short* Vbf = (unsigned short*)ws;  ws += (size_t)NPOS * 128 * 2;

    // 1. hi/lo expansion of x (A-side), qkv_w/proj_w (B-side)
    prep_kernel<<<784, 256, 0, stream>>>(x, qkv_w, proj_w, Axq, Bxq, Bxp);

    // 2. QKV GEMM -> Qhl (bf16 hi/lo), Kbf, Vbf (bf16)
    {
        dim3 grid(384 / 64, NPOS / 128);
        gemm_mfma_kernel<2, 1><<<grid, 256, 0, stream>>>(
            Axq, Bxq, qkv_b, nullptr, 0, Qhl, Kbf, Vbf);
    }
    // 3. fused neighborhood attention -> Ap (bf16 hi|lo|hi)
    {
        dim3 grid(72, NHEADS);
        attn_kernel<<<grid, 320, 0, stream>>>(Qhl, Kbf, Vbf, Ap);
    }
    // 4. proj GEMM: (5760x384bf16) @ (128x384bf16)^T -> out fp32
    {
        dim3 grid(DIMC / 64, NPOS / 64);
        gemm_mfma_kernel<1, 0><<<grid, 256, 0, stream>>>(
            Ap, Bxp, proj_b, out, DIMC, nullptr, nullptr, nullptr);
    }
}

// Round 7
// 109.008 us; speedup vs baseline: 1.0128x; 1.0128x over previous
//
#include <hip/hip_runtime.h>
#include <hip/hip_bf16.h>
#include <cstddef>

// Problem constants
#define DIMC   128
#define NHEADS 8
#define HDIM   16
#define DD     5
#define HH     24
#define WW_    48
#define NPOS   (DD * HH * WW_)     // 5760
#define SCALE  0.25f

typedef short  bf16x8 __attribute__((ext_vector_type(8)));
typedef float  f32x4  __attribute__((ext_vector_type(4)));

__device__ __forceinline__ unsigned short f2bf(float f) {
    unsigned u = __float_as_uint(f);
    u = (u + 0x7FFFu + ((u >> 16) & 1u)) >> 16;   // RNE
    return (unsigned short)u;
}
__device__ __forceinline__ float bf2f(unsigned short s) {
    return __uint_as_float(((unsigned)s) << 16);
}

// ---------------------------------------------------------------------------
// prep: fp32 -> bf16 3-term split expansion.
//   A-side (x):       [hi(128) | lo(128) | hi(128)]
//   B-side (weights): [hi(128) | hi(128) | lo(128)]
// Pairing: hi*hi + lo*hi + hi*lo == full product minus negligible lo*lo.
// ---------------------------------------------------------------------------
__global__ __launch_bounds__(256) void prep_kernel(
    const float* __restrict__ x,
    const float* __restrict__ wq,
    const float* __restrict__ wp,
    unsigned short* __restrict__ Axq,
    unsigned short* __restrict__ Bxq,
    unsigned short* __restrict__ Bxp)
{
    const int i = blockIdx.x * 256 + threadIdx.x;   // one float4 each
    const bool isA = (i < 184320);
    const float* src; unsigned short* dst; int rel;
    if (isA)             { src = x;  dst = Axq; rel = i; }
    else if (i < 196608) { src = wq; dst = Bxq; rel = i - 184320; }
    else                 { src = wp; dst = Bxp; rel = i - 196608; }
    const int row = rel >> 5;
    const int c4  = rel & 31;
    const float4 v = *(const float4*)(src + (size_t)row * 128 + c4 * 4);
    ushort4 hi, lo;
    hi.x = f2bf(v.x); hi.y = f2bf(v.y); hi.z = f2bf(v.z); hi.w = f2bf(v.w);
    lo.x = f2bf(v.x - bf2f(hi.x));
    lo.y = f2bf(v.y - bf2f(hi.y));
    lo.z = f2bf(v.z - bf2f(hi.z));
    lo.w = f2bf(v.w - bf2f(hi.w));
    unsigned short* p = dst + (size_t)row * 384 + c4 * 4;
    if (isA) {
        *(ushort4*)(p)       = hi;
        *(ushort4*)(p + 128) = lo;
        *(ushort4*)(p + 256) = hi;
    } else {
        *(ushort4*)(p)       = hi;
        *(ushort4*)(p + 128) = hi;
        *(ushort4*)(p + 256) = lo;
    }
}

// ---------------------------------------------------------------------------
// MFMA GEMM: C[M][N] = A'[M][384] @ B'[N][384]^T + bias.
// MI: rows per wave / 16. EPI 0: fp32 C out. EPI 1 (QKV): Q fp32 coalesced
// (hi/lo split deferred to attn staging), K/V bf16 (Kbf/Vbf[pos][128]).
// MI=1 grid (N/64, M/64): 540 blocks for qkv -> 2.1 blocks/CU.
// ---------------------------------------------------------------------------
template <int MI, int EPI>
__global__ __launch_bounds__(256, 3) void gemm_mfma_kernel(
    const unsigned short* __restrict__ Ax,
    const unsigned short* __restrict__ Bx,
    const float* __restrict__ bias,
    float* __restrict__ C, int ldc,
    float* __restrict__ Qf32,
    unsigned short* __restrict__ Kbf,
    unsigned short* __restrict__ Vbf)
{
    __shared__ __align__(16) unsigned short Bs[64][392];  // +16B row pad

    const int tid = threadIdx.x;
    const int bn  = blockIdx.x * 64;
    const int bm  = blockIdx.y * 64 * MI;

    for (int i = tid; i < 64 * 48; i += 256) {
        const int r = i / 48, s = i % 48;
        *(ulonglong2*)(&Bs[r][s * 8]) =
            *(const ulonglong2*)(Bx + (size_t)(bn + r) * 384 + s * 8);
    }
    __syncthreads();

    const int w    = tid >> 6;
    const int lane = tid & 63;
    const int ln   = lane & 15;
    const int quad = lane >> 4;

    f32x4 acc[MI][4] = {};
    const unsigned short* arow[MI];
    #pragma unroll
    for (int mi = 0; mi < MI; ++mi)
        arow[mi] = Ax + (size_t)(bm + w * 16 * MI + mi * 16 + ln) * 384 + quad * 8;

    #pragma unroll
    for (int kc = 0; kc < 12; ++kc) {
        bf16x8 a[MI];
        #pragma unroll
        for (int mi = 0; mi < MI; ++mi) a[mi] = *(const bf16x8*)(arow[mi] + kc * 32);
        #pragma unroll
        for (int nt = 0; nt < 4; ++nt) {
            const bf16x8 b = *(const bf16x8*)(&Bs[nt * 16 + ln][kc * 32 + quad * 8]);
            #pragma unroll
            for (int mi = 0; mi < MI; ++mi)
                acc[mi][nt] = __builtin_amdgcn_mfma_f32_16x16x32_bf16(a[mi], b, acc[mi][nt], 0, 0, 0);
        }
    }

    #pragma unroll
    for (int mi = 0; mi < MI; ++mi)
        #pragma unroll
        for (int nt = 0; nt < 4; ++nt) {
            const int col = bn + nt * 16 + ln;
            const float bv = bias[col];
            #pragma unroll
            for (int r = 0; r < 4; ++r) {
                const int row = bm + w * 16 * MI + mi * 16 + quad * 4 + r;
                const float val = acc[mi][nt][r] + bv;
                if (EPI == 0) {
                    C[(size_t)row * ldc + col] = val;
                } else {
                    if (col < 128) {               // q -> fp32, coalesced dwords
                        Qf32[(size_t)row * 128 + col] = val;
                    } else if (col < 256) {        // k -> bf16
                        Kbf[(size_t)row * 128 + (col - 128)] = f2bf(val);
                    } else {                       // v -> bf16
                        Vbf[(size_t)row * 128 + (col - 256)] = f2bf(val);
                    }
                }
            }
        }
}

// ---------------------------------------------------------------------------
// Fused neighborhood attention, wave-per-depth-slab + K-prefetch version.
// Grid (72 tiles of 4x4, 8 heads), 320 threads = 5 waves; wave w owns depth
// slab mt=w over ALL 512 union columns (zero inter-wave coupling, ONE
// barrier, direct global epilogue).
// Latency fix vs R6: K fragments for chunk c+1 are loaded from global at the
// top of iteration c (addresses from RowL LUT, independent of compute), so
// the score MFMA always consumes registers loaded a full iteration earlier —
// the ~200-900 cyc global latency leaves the per-chunk critical path.
// ---------------------------------------------------------------------------
__global__ __launch_bounds__(320, 2) void attn_kernel(
    const float* __restrict__ Qf32,           // [5760][128] fp32 q
    const unsigned short* __restrict__ Kbf,   // [5760][128] bf16
    const unsigned short* __restrict__ Vbf,   // [5760][128] bf16
    unsigned short* __restrict__ Ap)          // [5760][384] bf16 hi|lo|hi
{
    __shared__ __align__(16) unsigned short Vt[16][520];       // 16640 B  V^T
    __shared__ __align__(16) unsigned short Qb[80][40];        //  6400 B  [hi16|lo16|pad]
    __shared__ __align__(16) unsigned short Pw[5][2][16][40];  // 12800 B  per-wave P
    __shared__ unsigned short Mb2[16][34];                     //  1088 B  mask bits [ln][tile]
    __shared__ int RowL[512];                                  //  2048 B  u -> global row

    const int tile = blockIdx.x;
    const int h    = blockIdx.y;
    const int ty0  = (tile / 12) * 4;
    const int tx0  = (tile % 12) * 4;
    const int tid  = threadIdx.x;

    // ---- RowL LUT: u -> wrapped global position (clamped for u>=500) ----
    for (int u = tid; u < 512; u += 320) {
        const int uc = u < 500 ? u : 499;
        const int dp = uc / 100, rr = uc % 100;
        const int uy = rr / 10,  ux = rr % 10;
        int y = ty0 - 3 + uy; if (y < 0) y += HH;  if (y >= HH) y -= HH;
        int x = tx0 - 3 + ux; if (x < 0) x += WW_; if (x >= WW_) x -= WW_;
        RowL[u] = (dp * HH + y) * WW_ + x;
    }
    // ---- mask LUT: Mb2[ln][t] bit b = (u=16t+b valid for query ln) ----
    for (int i = tid; i < 512; i += 320) {
        const int t = i >> 4, ln = i & 15;
        const int sy = ln >> 2, sx = ln & 3;
        unsigned bits = 0;
        #pragma unroll
        for (int b = 0; b < 16; ++b) {
            const int u = t * 16 + b;
            const int rr = u % 100;
            const int uy = rr / 10, ux = rr % 10;
            if (u < 500 && (unsigned)(uy - sy) <= 6u && (unsigned)(ux - sx) <= 6u)
                bits |= 1u << b;
        }
        Mb2[ln][t] = (unsigned short)bits;
    }
    // ---- stage V^T: item = u-pair, dword-packed writes ----
    for (int i = tid; i < 256; i += 320) {
        const int u0 = i * 2;
        unsigned short va[16], vb[16];
        #pragma unroll
        for (int c = 0; c < 16; ++c) { va[c] = 0; vb[c] = 0; }
        #pragma unroll
        for (int half = 0; half < 2; ++half) {
            const int u = u0 + half;
            if (u < 500) {
                const int dp = u / 100, rr = u % 100;
                const int uy = rr / 10,  ux = rr % 10;
                int y = ty0 - 3 + uy; if (y < 0) y += HH;  if (y >= HH) y -= HH;
                int x = tx0 - 3 + ux; if (x < 0) x += WW_; if (x >= WW_) x -= WW_;
                const int g = (dp * HH + y) * WW_ + x;
                const bf16x8 p0 = *(const bf16x8*)(Vbf + (size_t)g * 128 + h * 16);
                const bf16x8 p1 = *(const bf16x8*)(Vbf + (size_t)g * 128 + h * 16 + 8);
                unsigned short* dst = half ? vb : va;
                #pragma unroll
                for (int c = 0; c < 8; ++c) { dst[c] = (unsigned short)p0[c]; dst[8 + c] = (unsigned short)p1[c]; }
            }
        }
        #pragma unroll
        for (int c = 0; c < 16; ++c)
            *(unsigned*)(&Vt[c][u0]) = (unsigned)va[c] | ((unsigned)vb[c] << 16);
    }
    // ---- stage Q tile: fp32 read, hi/lo split here (one-time) ----
    for (int i = tid; i < 1280; i += 320) {
        const int p = i >> 4, c = i & 15;
        const int d = p >> 4, s = p & 15;
        const int sy = s >> 2, sx = s & 3;
        const int g = (d * HH + ty0 + sy) * WW_ + tx0 + sx;
        const float qv = Qf32[(size_t)g * 128 + h * 16 + c];
        const unsigned short hi = f2bf(qv);
        Qb[p][c]      = hi;
        Qb[p][16 + c] = f2bf(qv - bf2f(hi));
    }
    __syncthreads();   // the only barrier

    const int w    = tid >> 6;    // wave = depth slab mt
    const int lane = tid & 63;
    const int ln   = lane & 15;
    const int quad = lane >> 4;

    const bf16x8 qf = *(const bf16x8*)(&Qb[w * 16 + ln][quad * 8]);
    f32x4 Ow = {0.f, 0.f, 0.f, 0.f};
    float lsum = 0.f;

    const float C1 = SCALE * 1.44269504f;   // log2(e)*scale
    const float C0 = -11.5415603f;          // -8*log2(e) (shift cancels in softmax)

    const int koff = h * 16 + (quad & 1) * 8;
    // prefetch chunk 0's K fragments
    bf16x8 k0 = *(const bf16x8*)(Kbf + (size_t)RowL[ln]      * 128 + koff);
    bf16x8 k1 = *(const bf16x8*)(Kbf + (size_t)RowL[16 + ln] * 128 + koff);

    #pragma unroll 2
    for (int c = 0; c < 16; ++c) {
        const int u0 = c * 32;
        // issue next chunk's K loads first (independent of everything below)
        bf16x8 n0 = k0, n1 = k1;
        if (c < 15) {
            const int g0 = RowL[u0 + 32 + ln];
            const int g1 = RowL[u0 + 48 + ln];
            n0 = *(const bf16x8*)(Kbf + (size_t)g0 * 128 + koff);
            n1 = *(const bf16x8*)(Kbf + (size_t)g1 * 128 + koff);
        }
        const unsigned mb = *(const unsigned*)(&Mb2[ln][2 * c]);   // tiles 2c|2c+1
        const unsigned m0 = (mb >> (quad * 4)) & 0xF;
        const unsigned m1 = (mb >> (16 + quad * 4)) & 0xF;

        f32x4 s0 = __builtin_amdgcn_mfma_f32_16x16x32_bf16(k0, qf, (f32x4){0.f,0.f,0.f,0.f}, 0, 0, 0);
        f32x4 s1 = __builtin_amdgcn_mfma_f32_16x16x32_bf16(k1, qf, (f32x4){0.f,0.f,0.f,0.f}, 0, 0, 0);

        unsigned short* pw = &Pw[w][c & 1][ln][0];
        #pragma unroll
        for (int t = 0; t < 2; ++t) {
            const f32x4 s = t ? s1 : s0;
            const unsigned m = t ? m1 : m0;
            unsigned eu[4];
            #pragma unroll
            for (int r = 0; r < 4; ++r) {
                const float arg = ((m >> r) & 1u) ? fmaf(s[r], C1, C0) : -100.f;
                const unsigned trunc = __float_as_uint(exp2f(arg)) & 0xFFFF0000u;
                eu[r] = trunc;
                lsum += __uint_as_float(trunc);
            }
            unsigned* dst = (unsigned*)(pw + t * 16 + quad * 4);
            dst[0] = (eu[0] >> 16) | eu[1];
            dst[1] = (eu[2] >> 16) | eu[3];
        }

        const bf16x8 vf = *(const bf16x8*)(&Vt[ln][u0 + quad * 8]);
        const bf16x8 pf = *(const bf16x8*)(&Pw[w][c & 1][ln][quad * 8]);
        Ow = __builtin_amdgcn_mfma_f32_16x16x32_bf16(vf, pf, Ow, 0, 0, 0);

        k0 = n0; k1 = n1;
    }

    // ---- l: reduce across quads (lanes ln+16q hold disjoint u-partials) ----
    lsum += __shfl_xor(lsum, 16);
    lsum += __shfl_xor(lsum, 32);
    const float inv = 1.0f / lsum;

    // ---- epilogue: lane holds O^T[ch=quad*4+r][query=ln], write Ap ----
    const int sy = ln >> 2, sx = ln & 3;
    const size_t g = (size_t)((w * HH + ty0 + sy) * WW_ + (tx0 + sx));
    ushort4 hi4, lo4;
    {
        float v0 = Ow[0] * inv, v1 = Ow[1] * inv, v2 = Ow[2] * inv, v3 = Ow[3] * inv;
        hi4.x = f2bf(v0); lo4.x = f2bf(v0 - bf2f(hi4.x));
        hi4.y = f2bf(v1); lo4.y = f2bf(v1 - bf2f(hi4.y));
        hi4.z = f2bf(v2); lo4.z = f2bf(v2 - bf2f(hi4.z));
        hi4.w = f2bf(v3); lo4.w = f2bf(v3 - bf2f(hi4.w));
    }
    unsigned short* row = Ap + g * 384 + h * HDIM + quad * 4;
    *(ushort4*)(row)       = hi4;
    *(ushort4*)(row + 128) = lo4;
    *(ushort4*)(row + 256) = hi4;
}

// ---------------------------------------------------------------------------
extern "C" void kernel_launch(void* const* d_in, const int* in_sizes, int n_in,
                              void* d_out, int out_size, void* d_ws, size_t ws_size,
                              hipStream_t stream)
{
    const float* x      = (const float*)d_in[0];
    const float* qkv_w  = (const float*)d_in[1];
    const float* qkv_b  = (const float*)d_in[2];
    const float* proj_w = (const float*)d_in[3];
    const float* proj_b = (const float*)d_in[4];
    float* out = (float*)d_out;

    char* ws = (char*)d_ws;
    unsigned short* Axq = (unsigned short*)ws;  ws += (size_t)NPOS * 384 * 2;  // x  hi|lo|hi
    unsigned short* Ap  = (unsigned short*)ws;  ws += (size_t)NPOS * 384 * 2;  // attn out hi|lo|hi
    unsigned short* Bxq = (unsigned short*)ws;  ws += (size_t)384 * 384 * 2;
    unsigned short* Bxp = (unsigned short*)ws;  ws += (size_t)128 * 384 * 2;
    float*          Qf  = (float*)ws;           ws += (size_t)NPOS * 128 * 4;  // q fp32
    unsigned short* Kbf = (unsigned short*)ws;  ws += (size_t)NPOS * 128 * 2;
    unsigned short* Vbf = (unsigned short*)ws;  ws += (size_t)NPOS * 128 * 2;

    // 1. hi/lo expansion of x (A-side), qkv_w/proj_w (B-side)
    prep_kernel<<<784, 256, 0, stream>>>(x, qkv_w, proj_w, Axq, Bxq, Bxp);

    // 2. QKV GEMM -> Qf (fp32), Kbf, Vbf (bf16); MI=1 for 540 blocks
    {
        dim3 grid(384 / 64, NPOS / 64);
        gemm_mfma_kernel<1, 1><<<grid, 256, 0, stream>>>(
            Axq, Bxq, qkv_b, nullptr, 0, Qf, Kbf, Vbf);
    }
    // 3. fused neighborhood attention -> Ap (bf16 hi|lo|hi)
    {
        dim3 grid(72, NHEADS);
        attn_kernel<<<grid, 320, 0, stream>>>(Qf, Kbf, Vbf, Ap);
    }
    // 4. proj GEMM: (5760x384bf16) @ (128x384bf16)^T -> out fp32
    {
        dim3 grid(DIMC / 64, NPOS / 64);
        gemm_mfma_kernel<1, 0><<<grid, 256, 0, stream>>>(
            Ap, Bxp, proj_b, out, DIMC, nullptr, nullptr, nullptr);
    }
}